// Round 9
// baseline (13.364 us; speedup 1.0000x reference)
//
#include <hip/hip_runtime.h>

typedef short  bf16x8 __attribute__((ext_vector_type(8)));
typedef float  f32x4  __attribute__((ext_vector_type(4)));

#define HP 4

// Swizzled chunk address (in shorts): row stride 72 shorts (144 B), data as
// 8 chunks of 8 shorts (16 B); chunk slot = cc ^ ((row>>3)&7).  For any 16
// consecutive rows at fixed cc this spreads banks to exactly 2-way (free).
#define TOFF(row, cc) ((row) * 72 + ((((cc) ^ (((row) >> 3) & 7))) << 3))

// ---------------------------------------------------------------------------
// Fused kernel: one block per (n, i) center-row. 224 blocks x 896 threads.
//
// Phase 1 (waves 0..9, ONE row each, zero coupling, one barrier): wave w
//   stages row w (0..8 -> B rows i-4..i+4, 9 -> A row i). Lane = w-coord;
//   64 raw fp32 loads into regs, per-lane ss (norms applied AFTER MFMA:
//   dot(a^,b^) = raw * inva[j] * invb[j']), v_cvt_pk_bf16_f32 pack,
//   swizzled ds_write_b128 into LDS tiles (stride 72 shorts + chunk XOR).
//
// Phase 2 (14 waves): half-task per wave: tt = w%7 -> (m = tt&3, ti = tt>>2),
//   half = w/7 -> di in [0,5) or [5,9), COMPILE-TIME UNROLLED; per di two
//   INDEPENDENT MFMAs (acc0+acc1 summed in fp32) -> scale, band-mask,
//   sum-exp/sum-x. s/sx merge additively in LDS; 56 parallel logs.
//
// Finish: plain store partials[b]; 1-wave reduce kernel -> d_out.
// ---------------------------------------------------------------------------
__global__ __launch_bounds__(896) void fused_kernel(const float* __restrict__ A,
                                                    const float* __restrict__ B,
                                                    float* __restrict__ partials) {
    __shared__ ushort bt[9][64 * 72];  // 82,944 B raw-bf16 B rows (swizzled chunks)
    __shared__ ushort at[64 * 72];     //  9,216 B raw-bf16 A row
    __shared__ float  binv[9][64];
    __shared__ float  ainv_s[64];
    __shared__ float  s_lds[14][16];
    __shared__ float  sx_lds[14][16];

    // Bijective XCD swizzle (224 = 8 * 28): i-neighbors share an L2
    const int b0 = blockIdx.x;
    const int b  = (b0 & 7) * 28 + (b0 >> 3);
    const int n  = b / 56;
    const int i  = b - n * 56 + HP;          // 4..59
    const int t  = threadIdx.x, wib = t >> 6, l = t & 63;

    // ---- Phase 1: waves 0..9 stage one row each (10..13 idle to barrier)
    if (wib < 10) {
        const int r = wib;                   // wave-uniform
        const int hrow = (r == 9) ? i : (i - HP + r);
        const float* src = ((r == 9) ? A : B) + (size_t)n * 262144 + (size_t)hrow * 64 + l;
        ushort* dst = (r == 9) ? at : bt[r];

        float v[64];
        #pragma unroll
        for (int c = 0; c < 64; ++c) v[c] = src[(size_t)c * 4096];

        float ss0 = 0.f, ss1 = 0.f, ss2 = 0.f, ss3 = 0.f;
        #pragma unroll
        for (int c = 0; c < 64; c += 4) {
            ss0 = fmaf(v[c],   v[c],   ss0);
            ss1 = fmaf(v[c+1], v[c+1], ss1);
            ss2 = fmaf(v[c+2], v[c+2], ss2);
            ss3 = fmaf(v[c+3], v[c+3], ss3);
        }
        #pragma unroll
        for (int c0 = 0; c0 < 64; c0 += 8) {
            uint pk[4];
            #pragma unroll
            for (int q = 0; q < 4; ++q)
                asm("v_cvt_pk_bf16_f32 %0, %1, %2"
                    : "=v"(pk[q]) : "v"(v[c0 + 2*q]), "v"(v[c0 + 2*q + 1]));
            *(uint4*)(dst + TOFF(l, c0 >> 3)) = *(const uint4*)pk;  // 16B aligned
        }
        const float inv = 1.0f / (sqrtf((ss0 + ss1) + (ss2 + ss3)) + 1e-8f);
        if (r == 9) ainv_s[l] = inv; else binv[r][l] = inv;
    }
    __syncthreads();

    // ---- Phase 2: 14 waves, wave = (task tt = w%7, di-half = w/7)
    const int lo = l & 15, hi = l >> 4;
    {
        const int tt   = (wib >= 7) ? (wib - 7) : wib;   // 0..6
        const int half = (wib >= 7) ? 1 : 0;
        const int m    = tt & 3, ti = tt >> 2;           // ti=1 only for m<=2
        const int ntv  = m + ti;                         // 0..3 (always valid)
        const int j0   = HP + m * 16;
        const int arow_l = min(j0 + lo, 63);             // clamped lanes feed masked rows
        const bf16x8 a0 = *(const bf16x8*)(at + TOFF(arow_l, hi));
        const bf16x8 a1 = *(const bf16x8*)(at + TOFF(arow_l, hi + 4));

        int jrow[4]; float av[4];
        #pragma unroll
        for (int r = 0; r < 4; ++r) {
            jrow[r] = j0 + hi * 4 + r;
            av[r]   = ainv_s[min(jrow[r], 63)];
        }

        const int col = ntv * 16 + lo;
        const int coff0 = TOFF(col, hi);         // chunk hi of row col
        const int coff1 = TOFF(col, hi + 4);     // chunk hi+4
        float vm[4];
        #pragma unroll
        for (int r = 0; r < 4; ++r) {
            int d = col - jrow[r];
            vm[r] = (jrow[r] < 60 && d >= -HP && d <= HP) ? 1.0f : 0.0f;
        }

        float s_acc[4]  = {0.f, 0.f, 0.f, 0.f};
        float sx_acc[4] = {0.f, 0.f, 0.f, 0.f};

        #define DI_BODY(di) {                                                        \
            const bf16x8 bq0 = *(const bf16x8*)(bt[di] + coff0);                     \
            const bf16x8 bq1 = *(const bf16x8*)(bt[di] + coff1);                     \
            f32x4 acc0 = __builtin_amdgcn_mfma_f32_16x16x32_bf16(a0, bq0,            \
                             (f32x4){0.f, 0.f, 0.f, 0.f}, 0, 0, 0);                  \
            f32x4 acc1 = __builtin_amdgcn_mfma_f32_16x16x32_bf16(a1, bq1,            \
                             (f32x4){0.f, 0.f, 0.f, 0.f}, 0, 0, 0);                  \
            const float bi = binv[di][col];                                          \
            _Pragma("unroll")                                                        \
            for (int r = 0; r < 4; ++r) {                                            \
                float p = (acc0[r] + acc1[r]) * (av[r] * bi);                        \
                float e = __expf(p);                                                 \
                s_acc[r]  = fmaf(vm[r], e, s_acc[r]);                                \
                sx_acc[r] = fmaf(vm[r], p, sx_acc[r]);                               \
            }                                                                        \
        }

        if (half == 0) {
            DI_BODY(0) DI_BODY(1) DI_BODY(2) DI_BODY(3) DI_BODY(4)
        } else {
            DI_BODY(5) DI_BODY(6) DI_BODY(7) DI_BODY(8)
        }
        #undef DI_BODY

        // reduce across the 16 col-lanes sharing each output row
        #pragma unroll
        for (int r = 0; r < 4; ++r) {
            #pragma unroll
            for (int off = 1; off < 16; off <<= 1) {
                s_acc[r]  += __shfl_xor(s_acc[r],  off);
                sx_acc[r] += __shfl_xor(sx_acc[r], off);
            }
        }
        if (lo == 0) {
            #pragma unroll
            for (int r = 0; r < 4; ++r) {
                s_lds[wib][hi * 4 + r]  = s_acc[r];
                sx_lds[wib][hi * 4 + r] = sx_acc[r];
            }
        }
    }
    __syncthreads();

    // ---- Per-block finish (wave 0): lane l <-> center j = HP + l
    // Band m2 gathers waves {m2, m2+7} plus {m2+4, m2+11} when m2 < 3.
    if (wib == 0) {
        float contrib = 0.f;
        if (l < 56) {
            const int m2 = l >> 4, rib = l & 15;
            float s  = s_lds[m2][rib]  + s_lds[m2 + 7][rib];
            float sx = sx_lds[m2][rib] + sx_lds[m2 + 7][rib];
            if (m2 < 3) {
                s  += s_lds[m2 + 4][rib]  + s_lds[m2 + 11][rib];
                sx += sx_lds[m2 + 4][rib] + sx_lds[m2 + 11][rib];
            }
            contrib = 81.0f * __logf(s) - sx;
        }
        #pragma unroll
        for (int off = 32; off; off >>= 1) contrib += __shfl_xor(contrib, off);
        if (l == 0) partials[b] = contrib;
    }
}

// ---------------------------------------------------------------------------
// Final reduce: one wave sums 224 partials -> d_out[0] (deterministic)
// ---------------------------------------------------------------------------
__global__ __launch_bounds__(64) void reduce_kernel(const float* __restrict__ partials,
                                                    float* __restrict__ out) {
    const int t = threadIdx.x;
    float s = 0.f;
    #pragma unroll
    for (int k = 0; k < 4; ++k) {
        int idx = k * 64 + t;
        if (idx < 224) s += partials[idx];
    }
    #pragma unroll
    for (int off = 32; off; off >>= 1) s += __shfl_xor(s, off);
    if (t == 0) out[0] = s;
}

extern "C" void kernel_launch(void* const* d_in, const int* in_sizes, int n_in,
                              void* d_out, int out_size, void* d_ws, size_t ws_size,
                              hipStream_t stream) {
    // inputs: 0=featsA(unused) 1=warpedA 2=tensorB 3=warp_grid(unused) 4=patch_size(=9)
    const float* warpedA = (const float*)d_in[1];
    const float* tensorB = (const float*)d_in[2];
    float* partials = (float*)d_ws;          // 224 floats
    float* out = (float*)d_out;

    fused_kernel<<<224, 896, 0, stream>>>(warpedA, tensorB, partials);
    reduce_kernel<<<1, 64, 0, stream>>>(partials, out);
}

// Round 10
// 13.207 us; speedup vs baseline: 1.0119x; 1.0119x over previous
//
#include <hip/hip_runtime.h>

typedef short  bf16x8 __attribute__((ext_vector_type(8)));
typedef float  f32x4  __attribute__((ext_vector_type(4)));

#define HP 4

// ---------------------------------------------------------------------------
// Fused kernel (R8 best-measured configuration, reverted from R9's neutral
// micro-opts): one block per (n, i) center-row. 224 blocks x 896 threads.
//
// Phase 1 (waves 0..9, ONE row each, zero coupling, one barrier): wave w
//   stages row w (0..8 -> B rows i-4..i+4, 9 -> A row i). Lane = w-coord;
//   64 raw fp32 loads into regs, per-lane ss (norms applied AFTER MFMA:
//   dot(a^,b^) = raw * inva[j] * invb[j']), v_cvt_pk_bf16_f32 pack (1 instr
//   per pair), ds_write_b128 into padded LDS tiles [w][72] (stride 144 B
//   already spreads 16-row b128 reads across all 32 banks: 2-way = free).
//
// Phase 2 (14 waves): half-task per wave: tt = w%7 -> (m = tt&3, ti = tt>>2),
//   half = w/7 -> di range [0,5) or [5,9). 8-10 MFMAs per wave; scale by
//   inva*invb, band-mask, accumulate sum-exp/sum-x; s/sx merge additively
//   in LDS (log after merge), 56 parallel logs in wave 0.
//
// Finish: plain store partials[b]; 1-wave reduce kernel -> d_out.
// ---------------------------------------------------------------------------
__global__ __launch_bounds__(896) void fused_kernel(const float* __restrict__ A,
                                                    const float* __restrict__ B,
                                                    float* __restrict__ partials) {
    __shared__ ushort bt[9][64][72];   // 82,944 B raw-bf16 B rows
    __shared__ ushort at[64][72];      //  9,216 B raw-bf16 A row
    __shared__ float  binv[9][64];
    __shared__ float  ainv_s[64];
    __shared__ float  s_lds[14][16];
    __shared__ float  sx_lds[14][16];

    // Bijective XCD swizzle (224 = 8 * 28): i-neighbors share an L2
    const int b0 = blockIdx.x;
    const int b  = (b0 & 7) * 28 + (b0 >> 3);
    const int n  = b / 56;
    const int i  = b - n * 56 + HP;          // 4..59
    const int t  = threadIdx.x, wib = t >> 6, l = t & 63;

    // ---- Phase 1: waves 0..9 stage one row each (10..13 idle to barrier)
    if (wib < 10) {
        const int r = wib;                   // wave-uniform
        const int hrow = (r == 9) ? i : (i - HP + r);
        const float* src = ((r == 9) ? A : B) + (size_t)n * 262144 + (size_t)hrow * 64 + l;
        ushort* dst = ((r == 9) ? &at[0][0] : &bt[r][0][0]) + l * 72;

        float v[64];
        #pragma unroll
        for (int c = 0; c < 64; ++c) v[c] = src[(size_t)c * 4096];

        float ss0 = 0.f, ss1 = 0.f, ss2 = 0.f, ss3 = 0.f;
        #pragma unroll
        for (int c = 0; c < 64; c += 4) {
            ss0 = fmaf(v[c],   v[c],   ss0);
            ss1 = fmaf(v[c+1], v[c+1], ss1);
            ss2 = fmaf(v[c+2], v[c+2], ss2);
            ss3 = fmaf(v[c+3], v[c+3], ss3);
        }
        #pragma unroll
        for (int c0 = 0; c0 < 64; c0 += 8) {
            uint pk[4];
            #pragma unroll
            for (int q = 0; q < 4; ++q)
                asm("v_cvt_pk_bf16_f32 %0, %1, %2"
                    : "=v"(pk[q]) : "v"(v[c0 + 2*q]), "v"(v[c0 + 2*q + 1]));
            *(uint4*)(dst + c0) = *(const uint4*)pk;   // 16B aligned (144|16, 2*c0|16)
        }
        const float inv = 1.0f / (sqrtf((ss0 + ss1) + (ss2 + ss3)) + 1e-8f);
        if (r == 9) ainv_s[l] = inv; else binv[r][l] = inv;
    }
    __syncthreads();

    // ---- Phase 2: 14 waves, wave = (task tt = w%7, di-half = w/7)
    const int lo = l & 15, hi = l >> 4;
    {
        const int tt   = (wib >= 7) ? (wib - 7) : wib;   // 0..6
        const int half = (wib >= 7) ? 1 : 0;
        const int m    = tt & 3, ti = tt >> 2;           // ti=1 only for m<=2
        const int ntv  = m + ti;                         // 0..3 (always valid)
        const int j0   = HP + m * 16;
        const int arow_l = min(j0 + lo, 63);             // clamped lanes feed masked rows
        const bf16x8 a0 = *(const bf16x8*)&at[arow_l][hi * 8];
        const bf16x8 a1 = *(const bf16x8*)&at[arow_l][hi * 8 + 32];

        int jrow[4]; float av[4];
        #pragma unroll
        for (int r = 0; r < 4; ++r) {
            jrow[r] = j0 + hi * 4 + r;
            av[r]   = ainv_s[min(jrow[r], 63)];
        }

        const int col = ntv * 16 + lo;
        float vm[4];
        #pragma unroll
        for (int r = 0; r < 4; ++r) {
            int d = col - jrow[r];
            vm[r] = (jrow[r] < 60 && d >= -HP && d <= HP) ? 1.0f : 0.0f;
        }

        float s_acc[4]  = {0.f, 0.f, 0.f, 0.f};
        float sx_acc[4] = {0.f, 0.f, 0.f, 0.f};

        const int d0 = half ? 5 : 0, d1 = half ? 9 : 5;
        for (int di = d0; di < d1; ++di) {
            const ushort* q = &bt[di][col][hi * 8];
            const bf16x8 bq0 = *(const bf16x8*)q;
            const bf16x8 bq1 = *(const bf16x8*)(q + 32);
            f32x4 acc = __builtin_amdgcn_mfma_f32_16x16x32_bf16(a0, bq0,
                            (f32x4){0.f, 0.f, 0.f, 0.f}, 0, 0, 0);
            acc = __builtin_amdgcn_mfma_f32_16x16x32_bf16(a1, bq1, acc, 0, 0, 0);
            const float bi = binv[di][col];
            #pragma unroll
            for (int r = 0; r < 4; ++r) {
                float p = acc[r] * (av[r] * bi);
                float e = __expf(p);
                s_acc[r]  = fmaf(vm[r], e, s_acc[r]);
                sx_acc[r] = fmaf(vm[r], p, sx_acc[r]);
            }
        }
        // reduce across the 16 col-lanes sharing each output row
        #pragma unroll
        for (int r = 0; r < 4; ++r) {
            #pragma unroll
            for (int off = 1; off < 16; off <<= 1) {
                s_acc[r]  += __shfl_xor(s_acc[r],  off);
                sx_acc[r] += __shfl_xor(sx_acc[r], off);
            }
        }
        if (lo == 0) {
            #pragma unroll
            for (int r = 0; r < 4; ++r) {
                s_lds[wib][hi * 4 + r]  = s_acc[r];
                sx_lds[wib][hi * 4 + r] = sx_acc[r];
            }
        }
    }
    __syncthreads();

    // ---- Per-block finish (wave 0): lane l <-> center j = HP + l
    // Band m2 gathers waves {m2, m2+7} plus {m2+4, m2+11} when m2 < 3.
    if (wib == 0) {
        float contrib = 0.f;
        if (l < 56) {
            const int m2 = l >> 4, rib = l & 15;
            float s  = s_lds[m2][rib]  + s_lds[m2 + 7][rib];
            float sx = sx_lds[m2][rib] + sx_lds[m2 + 7][rib];
            if (m2 < 3) {
                s  += s_lds[m2 + 4][rib]  + s_lds[m2 + 11][rib];
                sx += sx_lds[m2 + 4][rib] + sx_lds[m2 + 11][rib];
            }
            contrib = 81.0f * __logf(s) - sx;
        }
        #pragma unroll
        for (int off = 32; off; off >>= 1) contrib += __shfl_xor(contrib, off);
        if (l == 0) partials[b] = contrib;
    }
}

// ---------------------------------------------------------------------------
// Final reduce: one wave sums 224 partials -> d_out[0] (deterministic)
// ---------------------------------------------------------------------------
__global__ __launch_bounds__(64) void reduce_kernel(const float* __restrict__ partials,
                                                    float* __restrict__ out) {
    const int t = threadIdx.x;
    float s = 0.f;
    #pragma unroll
    for (int k = 0; k < 4; ++k) {
        int idx = k * 64 + t;
        if (idx < 224) s += partials[idx];
    }
    #pragma unroll
    for (int off = 32; off; off >>= 1) s += __shfl_xor(s, off);
    if (t == 0) out[0] = s;
}

extern "C" void kernel_launch(void* const* d_in, const int* in_sizes, int n_in,
                              void* d_out, int out_size, void* d_ws, size_t ws_size,
                              hipStream_t stream) {
    // inputs: 0=featsA(unused) 1=warpedA 2=tensorB 3=warp_grid(unused) 4=patch_size(=9)
    const float* warpedA = (const float*)d_in[1];
    const float* tensorB = (const float*)d_in[2];
    float* partials = (float*)d_ws;          // 224 floats
    float* out = (float*)d_out;

    fused_kernel<<<224, 896, 0, stream>>>(warpedA, tensorB, partials);
    reduce_kernel<<<1, 64, 0, stream>>>(partials, out);
}